// Round 1
// baseline (837.113 us; speedup 1.0000x reference)
//
#include <hip/hip_runtime.h>
#include <hip/hip_bf16.h>
#include <math.h>

// Sizes (fixed by setup_inputs): B=32, W=2048, chans 64->128->256, E=1.
#define BATCH 32
#define WLEN  2048

// ---------------------------------------------------------------------------
// Routing: r[b] = sigmoid( (1/W) * sum_{i,w} fcw[i]*x[b,i,w] + fcb[0] )
// One block per sample. E=1 only.
// ---------------------------------------------------------------------------
template<int C>
__global__ __launch_bounds__(256) void routing_kernel(
    const float* __restrict__ x, const float* __restrict__ fcw,
    const float* __restrict__ fcb, float* __restrict__ r) {
  const int b = blockIdx.x;
  const int tid = threadIdx.x;
  const float4* xb = (const float4*)(x + (size_t)b * C * WLEN);
  const int n4 = C * (WLEN / 4);
  float sum = 0.f;
  for (int idx = tid; idx < n4; idx += 256) {
    float4 v = xb[idx];
    int i = idx >> 9;  // WLEN/4 = 512 float4 per channel row
    sum += (v.x + v.y + v.z + v.w) * fcw[i];
  }
  __shared__ float red[256];
  red[tid] = sum;
  __syncthreads();
  for (int s = 128; s > 0; s >>= 1) {
    if (tid < s) red[tid] += red[tid + s];
    __syncthreads();
  }
  if (tid == 0) {
    float z = red[0] * (1.f / (float)WLEN) + fcb[0];
    r[b] = 1.f / (1.f + expf(-z));
  }
}

// ---------------------------------------------------------------------------
// Fused conv1d(k=3,pad=1) * r_b + r_b*bias -> BN(eval) -> LeakyReLU(0.1)
// [-> maxpool2 if DO_POOL].
// Tile: 64 outputs (o) x 128 positions (w) per block, 256 threads,
// micro-tile 4 o x 8 w per thread. K staged in LDS in chunks of 16 channels.
// ---------------------------------------------------------------------------
template<int CIN, int COUT, int DO_POOL>
__global__ __launch_bounds__(256) void conv_block(
    const float* __restrict__ x, const float* __restrict__ wgt,
    const float* __restrict__ bias, const float* __restrict__ g,
    const float* __restrict__ be, const float* __restrict__ rm,
    const float* __restrict__ rv, const float* __restrict__ rbuf,
    float* __restrict__ out) {
  constexpr int W_T = 128;
  constexpr int O_T = 64;
  constexpr int KC = 16;

  const int b = blockIdx.z;
  const int o_base = blockIdx.y * O_T;
  const int w_base = blockIdx.x * W_T;
  const int tid = threadIdx.x;
  const int tw = tid & 15;   // w group: positions tw*8 .. tw*8+7
  const int to = tid >> 4;   // o group: outputs to*4 .. to*4+3

  __shared__ float xs[KC][W_T + 2];     // halo of 1 on each side
  __shared__ float wl[KC][O_T * 3];     // [i][o*3+k]

  float acc[4][8];
#pragma unroll
  for (int oo = 0; oo < 4; ++oo)
#pragma unroll
    for (int j = 0; j < 8; ++j) acc[oo][j] = 0.f;

  const float* xb = x + (size_t)b * CIN * WLEN;

  for (int i0 = 0; i0 < CIN; i0 += KC) {
    // stage x tile (with halo, zero-padded at W boundaries)
    for (int idx = tid; idx < KC * (W_T + 2); idx += 256) {
      int i = idx / (W_T + 2);
      int j = idx - i * (W_T + 2);
      int gw = w_base - 1 + j;
      float v = 0.f;
      if ((unsigned)gw < (unsigned)WLEN) v = xb[(size_t)(i0 + i) * WLEN + gw];
      xs[i][j] = v;
    }
    // stage weights: wl[i][o*3+k] = wgt[((o_base+o)*CIN + i0+i)*3 + k]
    for (int idx = tid; idx < KC * O_T * 3; idx += 256) {
      int i = idx / (O_T * 3);
      int rr = idx - i * (O_T * 3);  // o*3+k
      int o = rr / 3;
      int k = rr - o * 3;
      wl[i][rr] = wgt[((size_t)(o_base + o) * CIN + (i0 + i)) * 3 + k];
    }
    __syncthreads();

#pragma unroll
    for (int i = 0; i < KC; ++i) {
      float xv[10];
#pragma unroll
      for (int j = 0; j < 10; ++j) xv[j] = xs[i][tw * 8 + j];
#pragma unroll
      for (int oo = 0; oo < 4; ++oo) {
        const int wb0 = (to * 4 + oo) * 3;
        float w0 = wl[i][wb0 + 0];
        float w1 = wl[i][wb0 + 1];
        float w2 = wl[i][wb0 + 2];
#pragma unroll
        for (int j = 0; j < 8; ++j)
          acc[oo][j] += w0 * xv[j] + w1 * xv[j + 1] + w2 * xv[j + 2];
      }
    }
    __syncthreads();
  }

  // epilogue: y = (r*acc + r*bias - rm)*s + be ; leaky ; [pool]
  const float rb = rbuf[b];
#pragma unroll
  for (int oo = 0; oo < 4; ++oo) {
    const int o = o_base + to * 4 + oo;
    const float s = g[o] * rsqrtf(rv[o] + 1e-5f);
    const float a = rb * s;
    const float c = (rb * bias[o] - rm[o]) * s + be[o];
    if (DO_POOL) {
      float p[4];
#pragma unroll
      for (int j = 0; j < 4; ++j) {
        float y0 = acc[oo][2 * j] * a + c;
        y0 = y0 >= 0.f ? y0 : 0.1f * y0;
        float y1 = acc[oo][2 * j + 1] * a + c;
        y1 = y1 >= 0.f ? y1 : 0.1f * y1;
        p[j] = fmaxf(y0, y1);
      }
      float4 v = make_float4(p[0], p[1], p[2], p[3]);
      *(float4*)&out[((size_t)b * COUT + o) * (WLEN / 2) + (w_base >> 1) + tw * 4] = v;
    } else {
      float y[8];
#pragma unroll
      for (int j = 0; j < 8; ++j) {
        float yv = acc[oo][j] * a + c;
        y[j] = yv >= 0.f ? yv : 0.1f * yv;
      }
      float* dst = &out[((size_t)b * COUT + o) * WLEN + w_base + tw * 8];
      *(float4*)(dst + 0) = make_float4(y[0], y[1], y[2], y[3]);
      *(float4*)(dst + 4) = make_float4(y[4], y[5], y[6], y[7]);
    }
  }
}

// ---------------------------------------------------------------------------
extern "C" void kernel_launch(void* const* d_in, const int* in_sizes, int n_in,
                              void* d_out, int out_size, void* d_ws, size_t ws_size,
                              hipStream_t stream) {
  const float* x    = (const float*)d_in[0];
  const float* w1   = (const float*)d_in[1];
  const float* b1   = (const float*)d_in[2];
  const float* fcw1 = (const float*)d_in[3];
  const float* fcb1 = (const float*)d_in[4];
  const float* g1   = (const float*)d_in[5];
  const float* be1  = (const float*)d_in[6];
  const float* rm1  = (const float*)d_in[7];
  const float* rv1  = (const float*)d_in[8];
  const float* w2   = (const float*)d_in[9];
  const float* b2   = (const float*)d_in[10];
  const float* fcw2 = (const float*)d_in[11];
  const float* fcb2 = (const float*)d_in[12];
  const float* g2   = (const float*)d_in[13];
  const float* be2  = (const float*)d_in[14];
  const float* rm2  = (const float*)d_in[15];
  const float* rv2  = (const float*)d_in[16];

  float* out = (float*)d_out;
  // workspace layout: y1 (32*128*2048 f32 = 32 MiB), then r1(32), r2(32)
  float* y1 = (float*)d_ws;
  float* rr = (float*)((char*)d_ws + (size_t)BATCH * 128 * WLEN * sizeof(float));
  float* r1 = rr;
  float* r2 = rr + 32;

  routing_kernel<64><<<BATCH, 256, 0, stream>>>(x, fcw1, fcb1, r1);
  conv_block<64, 128, 0><<<dim3(WLEN / 128, 128 / 64, BATCH), 256, 0, stream>>>(
      x, w1, b1, g1, be1, rm1, rv1, r1, y1);
  routing_kernel<128><<<BATCH, 256, 0, stream>>>(y1, fcw2, fcb2, r2);
  conv_block<128, 256, 1><<<dim3(WLEN / 128, 256 / 64, BATCH), 256, 0, stream>>>(
      y1, w2, b2, g2, be2, rm2, rv2, r2, out);
}

// Round 2
// 80.916 us; speedup vs baseline: 10.3454x; 10.3454x over previous
//
#include <hip/hip_runtime.h>
#include <hip/hip_bf16.h>
#include <math.h>

#define BATCH 32
#define WLEN  2048

typedef __attribute__((ext_vector_type(8))) short short8;
typedef __attribute__((ext_vector_type(4))) short short4v;
typedef __attribute__((ext_vector_type(4))) float floatx4;

__device__ inline short f2bf(float f) {
  unsigned u = __float_as_uint(f);
  unsigned r = (u + 0x7fffu + ((u >> 16) & 1u)) >> 16;
  return (short)r;
}
__device__ inline float bf2f(short s) {
  return __uint_as_float(((unsigned)(unsigned short)s) << 16);
}

// ---------------------------------------------------------------------------
// prep: pack conv weights fp32 -> bf16 in [k][i/8][o][8] layout.
// blocks 0..11 -> w1 (128x64x3), blocks 12..59 -> w2 (256x128x3)
// ---------------------------------------------------------------------------
__global__ __launch_bounds__(256) void prep_w(
    const float* __restrict__ w1, const float* __restrict__ w2,
    short* __restrict__ wp1, short* __restrict__ wp2) {
  int blk = blockIdx.x;
  if (blk < 12) {
    int iw = blk * 256 + threadIdx.x;          // (k, ig, o) over 3*8*128
    int o = iw & 127;
    int t = iw >> 7;
    int ig = t & 7;
    int k = t >> 3;
    short8 v;
#pragma unroll
    for (int e = 0; e < 8; ++e) v[e] = f2bf(w1[(o * 64 + ig * 8 + e) * 3 + k]);
    *(short8*)(wp1 + ((size_t)iw) * 8) = v;  // ((k*8+ig)*128+o)*8 == iw*8
  } else {
    int iw = (blk - 12) * 256 + threadIdx.x;   // (k, ig, o) over 3*16*256
    int o = iw & 255;
    int t = iw >> 8;
    int ig = t & 15;
    int k = t >> 4;
    short8 v;
#pragma unroll
    for (int e = 0; e < 8; ++e) v[e] = f2bf(w2[(o * 128 + ig * 8 + e) * 3 + k]);
    *(short8*)(wp2 + ((size_t)iw) * 8) = v;
  }
}

// ---------------------------------------------------------------------------
// pack x fp32 (B,64,W) -> bf16 [b][ig=8][w][8]
// ---------------------------------------------------------------------------
__global__ __launch_bounds__(256) void pack_x(
    const float* __restrict__ x, short* __restrict__ xp) {
  int idx = blockIdx.x * 256 + threadIdx.x;    // (b, ig, w) over 32*8*2048
  int b = idx >> 14;
  int rem = idx & 16383;
  int ig = rem >> 11;
  int w = rem & 2047;
  const float* src = x + ((size_t)b * 64 + ig * 8) * WLEN + w;
  short8 v;
#pragma unroll
  for (int e = 0; e < 8; ++e) v[e] = f2bf(src[(size_t)e * WLEN]);
  *(short8*)(xp + (size_t)idx * 8) = v;
}

// ---------------------------------------------------------------------------
// routing partials, fp32 input: racc[b*8+j] = sum over channels [j*8,j*8+8)
// of fcw[i]*x[b,i,w] (all w). grid (8, 32).
// ---------------------------------------------------------------------------
__global__ __launch_bounds__(256) void routing_f32(
    const float* __restrict__ x, const float* __restrict__ fcw,
    float* __restrict__ racc) {
  const int j = blockIdx.x, b = blockIdx.y, tid = threadIdx.x;
  const float4* xb = (const float4*)(x + ((size_t)b * 64 + j * 8) * WLEN);
  float sum = 0.f;
  for (int idx = tid; idx < 8 * 512; idx += 256) {
    int c = idx >> 9;
    float4 v = xb[idx];
    sum += (v.x + v.y + v.z + v.w) * fcw[j * 8 + c];
  }
  __shared__ float red[256];
  red[tid] = sum;
  __syncthreads();
  for (int s = 128; s > 0; s >>= 1) {
    if (tid < s) red[tid] += red[tid + s];
    __syncthreads();
  }
  if (tid == 0) racc[b * 8 + j] = red[0];
}

// ---------------------------------------------------------------------------
// routing partials, packed bf16 input [b][16][w][8]: slice j covers ig {2j,2j+1}
// ---------------------------------------------------------------------------
__global__ __launch_bounds__(256) void routing_bf16(
    const short* __restrict__ yp, const float* __restrict__ fcw,
    float* __restrict__ racc) {
  const int j = blockIdx.x, b = blockIdx.y, tid = threadIdx.x;
  float fw[2][8];
#pragma unroll
  for (int q = 0; q < 2; ++q)
#pragma unroll
    for (int e = 0; e < 8; ++e) fw[q][e] = fcw[(j * 2 + q) * 8 + e];
  const short* base = yp + ((size_t)b * 16 + j * 2) * WLEN * 8;
  float sum = 0.f;
  for (int idx = tid; idx < 2 * WLEN; idx += 256) {
    int q = idx >> 11;
    int w = idx & 2047;
    short8 v = *(const short8*)(base + ((size_t)q * WLEN + w) * 8);
#pragma unroll
    for (int e = 0; e < 8; ++e) sum += bf2f(v[e]) * fw[q][e];
  }
  __shared__ float red[256];
  red[tid] = sum;
  __syncthreads();
  for (int s = 128; s > 0; s >>= 1) {
    if (tid < s) red[tid] += red[tid + s];
    __syncthreads();
  }
  if (tid == 0) racc[b * 8 + j] = red[0];
}

// ---------------------------------------------------------------------------
// MFMA conv block: y = BN(leaky?) no -- conv*r + r*bias -> BN -> leaky [-> pool]
// xp: bf16 packed [b][CIN/8][W][8]; wp: bf16 [k][CIN/8][COUT][8]
// tile: 64 Cout x 256 W, 4 waves (each 64x64 via 4x4 16x16 frags)
// ---------------------------------------------------------------------------
template<int CIN, int COUT, int DO_POOL>
__global__ __launch_bounds__(256) void conv_mfma(
    const short* __restrict__ xp, const short* __restrict__ wp,
    const float* __restrict__ bias, const float* __restrict__ g,
    const float* __restrict__ be, const float* __restrict__ rm,
    const float* __restrict__ rv, const float* __restrict__ racc,
    const float* __restrict__ fcb, void* __restrict__ outv) {
  constexpr int NIG = CIN / 8;
  const int b = blockIdx.z;
  const int o_base = blockIdx.y * 64;
  const int w_base = blockIdx.x * 256;
  const int tid = threadIdx.x;
  const int wave = tid >> 6, lane = tid & 63;
  const int ln = lane & 15, kg = lane >> 4;

  __shared__ short xs[4 * 258 * 8];

  floatx4 acc[4][4];
#pragma unroll
  for (int ms = 0; ms < 4; ++ms)
#pragma unroll
    for (int ns = 0; ns < 4; ++ns) acc[ms][ns] = (floatx4){0.f, 0.f, 0.f, 0.f};

  const short* xpb = xp + (size_t)b * NIG * WLEN * 8;

  for (int i0 = 0; i0 < CIN; i0 += 32) {
    if (i0) __syncthreads();
    // stage x tile: xs[ig][p][e] = x[i0+ig*8+e][w_base-1+p], p in [0,258)
    for (int idx = tid; idx < 4 * 258; idx += 256) {
      int ig = idx / 258;
      int p = idx - ig * 258;
      int w = w_base - 1 + p;
      short8 v = {0, 0, 0, 0, 0, 0, 0, 0};
      if ((unsigned)w < (unsigned)WLEN)
        v = *(const short8*)(xpb + ((size_t)((i0 >> 3) + ig) * WLEN + w) * 8);
      *(short8*)(xs + (ig * 258 + p) * 8) = v;
    }
    __syncthreads();

#pragma unroll
    for (int k = 0; k < 3; ++k) {
      short8 af[4], bfr[4];
      const short* wpk =
          wp + ((size_t)(k * NIG + (i0 >> 3) + kg) * COUT + o_base + ln) * 8;
#pragma unroll
      for (int ms = 0; ms < 4; ++ms)
        af[ms] = *(const short8*)(wpk + (size_t)ms * 16 * 8);
#pragma unroll
      for (int ns = 0; ns < 4; ++ns)
        bfr[ns] = *(const short8*)(xs + (kg * 258 + wave * 64 + ns * 16 + ln + k) * 8);
#pragma unroll
      for (int ms = 0; ms < 4; ++ms)
#pragma unroll
        for (int ns = 0; ns < 4; ++ns)
          acc[ms][ns] = __builtin_amdgcn_mfma_f32_16x16x32_bf16(
              af[ms], bfr[ns], acc[ms][ns], 0, 0, 0);
    }
  }

  // routing scalar
  float zs = 0.f;
#pragma unroll
  for (int q = 0; q < 8; ++q) zs += racc[b * 8 + q];
  float z = zs * (1.f / (float)WLEN) + fcb[0];
  float r = 1.f / (1.f + expf(-z));

#pragma unroll
  for (int ms = 0; ms < 4; ++ms) {
    const int o0 = o_base + ms * 16 + kg * 4;
    float a_[4], c_[4];
#pragma unroll
    for (int rr = 0; rr < 4; ++rr) {
      int o = o0 + rr;
      float s = g[o] * rsqrtf(rv[o] + 1e-5f);
      a_[rr] = r * s;
      c_[rr] = (r * bias[o] - rm[o]) * s + be[o];
    }
    if (DO_POOL) {
      float* out = (float*)outv;
#pragma unroll
      for (int ns = 0; ns < 4; ++ns) {
        int w = w_base + wave * 64 + ns * 16 + ln;
#pragma unroll
        for (int rr = 0; rr < 4; ++rr) {
          float v = acc[ms][ns][rr] * a_[rr] + c_[rr];
          v = v >= 0.f ? v : 0.1f * v;
          float ov = __shfl_xor(v, 1);
          float m = fmaxf(v, ov);
          if (!(lane & 1))
            out[((size_t)b * COUT + (o0 + rr)) * (WLEN / 2) + (w >> 1)] = m;
        }
      }
    } else {
      short* yp = (short*)outv;  // packed [b][COUT/8][W][8]
#pragma unroll
      for (int ns = 0; ns < 4; ++ns) {
        int w = w_base + wave * 64 + ns * 16 + ln;
        short4v pk;
#pragma unroll
        for (int rr = 0; rr < 4; ++rr) {
          float v = acc[ms][ns][rr] * a_[rr] + c_[rr];
          v = v >= 0.f ? v : 0.1f * v;
          pk[rr] = f2bf(v);
        }
        *(short4v*)(yp + ((size_t)(b * (COUT / 8) + (o0 >> 3)) * WLEN + w) * 8 +
                    (o0 & 7)) = pk;
      }
    }
  }
}

// ---------------------------------------------------------------------------
extern "C" void kernel_launch(void* const* d_in, const int* in_sizes, int n_in,
                              void* d_out, int out_size, void* d_ws, size_t ws_size,
                              hipStream_t stream) {
  const float* x    = (const float*)d_in[0];
  const float* w1   = (const float*)d_in[1];
  const float* b1   = (const float*)d_in[2];
  const float* fcw1 = (const float*)d_in[3];
  const float* fcb1 = (const float*)d_in[4];
  const float* g1   = (const float*)d_in[5];
  const float* be1  = (const float*)d_in[6];
  const float* rm1  = (const float*)d_in[7];
  const float* rv1  = (const float*)d_in[8];
  const float* w2   = (const float*)d_in[9];
  const float* b2   = (const float*)d_in[10];
  const float* fcw2 = (const float*)d_in[11];
  const float* fcb2 = (const float*)d_in[12];
  const float* g2   = (const float*)d_in[13];
  const float* be2  = (const float*)d_in[14];
  const float* rm2  = (const float*)d_in[15];
  const float* rv2  = (const float*)d_in[16];

  float* out = (float*)d_out;

  // workspace layout
  char* ws = (char*)d_ws;
  short* xp  = (short*)ws;                                  // 32*8*2048*8*2  = 8 MiB
  short* y1p = (short*)(ws + (size_t)8 * 1024 * 1024);      // 32*16*2048*8*2 = 16 MiB
  short* wp1 = (short*)(ws + (size_t)24 * 1024 * 1024);     // 3*8*128*8*2   = 48 KiB
  short* wp2 = (short*)(ws + (size_t)24 * 1024 * 1024 + 64 * 1024);   // 192 KiB
  float* racc1 = (float*)(ws + (size_t)25 * 1024 * 1024);   // 256 f
  float* racc2 = racc1 + 256;

  prep_w<<<60, 256, 0, stream>>>(w1, w2, wp1, wp2);
  pack_x<<<2048, 256, 0, stream>>>(x, xp);
  routing_f32<<<dim3(8, 32), 256, 0, stream>>>(x, fcw1, racc1);
  conv_mfma<64, 128, 0><<<dim3(8, 2, 32), 256, 0, stream>>>(
      xp, wp1, b1, g1, be1, rm1, rv1, racc1, fcb1, (void*)y1p);
  routing_bf16<<<dim3(8, 32), 256, 0, stream>>>(y1p, fcw2, racc2);
  conv_mfma<128, 256, 1><<<dim3(8, 4, 32), 256, 0, stream>>>(
      y1p, wp2, b2, g2, be2, rm2, rv2, racc2, fcb2, (void*)out);
}

// Round 3
// 57.536 us; speedup vs baseline: 14.5493x; 1.4064x over previous
//
#include <hip/hip_runtime.h>
#include <hip/hip_bf16.h>
#include <math.h>

#define BATCH 32
#define WLEN  2048

typedef __attribute__((ext_vector_type(8))) short short8;
typedef __attribute__((ext_vector_type(4))) short short4v;
typedef __attribute__((ext_vector_type(4))) float floatx4;

__device__ inline short f2bf(float f) {
  unsigned u = __float_as_uint(f);
  unsigned r = (u + 0x7fffu + ((u >> 16) & 1u)) >> 16;
  return (short)r;
}

// ---------------------------------------------------------------------------
// fused prep: blocks 0..11 pack w1 -> wp1[k][ig8][o128][8]
//             blocks 12..59 pack w2 -> wp2[k][ig16][o256][8]
//             blocks 60..315 routing1 partials racc1[b*8+j]
// ---------------------------------------------------------------------------
__global__ __launch_bounds__(256) void fused_prep(
    const float* __restrict__ w1, const float* __restrict__ w2,
    const float* __restrict__ x, const float* __restrict__ fcw1,
    short* __restrict__ wp1, short* __restrict__ wp2,
    float* __restrict__ racc1) {
  const int blk = blockIdx.x;
  const int tid = threadIdx.x;
  if (blk < 12) {
    int iw = blk * 256 + tid;          // (k, ig, o) over 3*8*128
    int o = iw & 127;
    int t = iw >> 7;
    int ig = t & 7;
    int k = t >> 3;
    short8 v;
#pragma unroll
    for (int e = 0; e < 8; ++e) v[e] = f2bf(w1[(o * 64 + ig * 8 + e) * 3 + k]);
    *(short8*)(wp1 + (size_t)iw * 8) = v;
  } else if (blk < 60) {
    int iw = (blk - 12) * 256 + tid;   // (k, ig, o) over 3*16*256
    int o = iw & 255;
    int t = iw >> 8;
    int ig = t & 15;
    int k = t >> 4;
    short8 v;
#pragma unroll
    for (int e = 0; e < 8; ++e) v[e] = f2bf(w2[(o * 128 + ig * 8 + e) * 3 + k]);
    *(short8*)(wp2 + (size_t)iw * 8) = v;
  } else {
    int t = blk - 60;
    int j = t & 7, b = t >> 3;
    const float4* xb = (const float4*)(x + ((size_t)b * 64 + j * 8) * WLEN);
    float sum = 0.f;
    for (int idx = tid; idx < 8 * 512; idx += 256) {
      int c = idx >> 9;
      float4 v = xb[idx];
      sum += (v.x + v.y + v.z + v.w) * fcw1[j * 8 + c];
    }
    __shared__ float red[256];
    red[tid] = sum;
    __syncthreads();
    for (int s = 128; s > 0; s >>= 1) {
      if (tid < s) red[tid] += red[tid + s];
      __syncthreads();
    }
    if (tid == 0) racc1[b * 8 + j] = red[0];
  }
}

// ---------------------------------------------------------------------------
// conv1: x fp32 (B,64,W) -> y1p bf16 [b][o/4][w][4], + routing2 partials.
// block = 512 thr (8 waves), tile 128o x 128w; wave = 64o x 32w (4ms x 2ns).
// grid (16, 32).
// ---------------------------------------------------------------------------
__global__ __launch_bounds__(512) void conv1_mfma(
    const float* __restrict__ x, const short* __restrict__ wp1,
    const float* __restrict__ bias, const float* __restrict__ g,
    const float* __restrict__ be, const float* __restrict__ rm,
    const float* __restrict__ rv, const float* __restrict__ racc1,
    const float* __restrict__ fcb, const float* __restrict__ fcw2,
    short* __restrict__ y1p, float* __restrict__ racc2) {
  const int b = blockIdx.y;
  const int w_base = blockIdx.x * 128;
  const int tid = threadIdx.x;
  const int wave = tid >> 6, lane = tid & 63;
  const int ln = lane & 15, kg = lane >> 4;
  const int oh = wave & 1, wq = wave >> 1;

  __shared__ short xs[8 * 130 * 8];   // [ig][p][e], p covers w_base-1..+128
  __shared__ float red[512];

  // stage all 64 input channels (fp32 -> bf16)
  const float* xb = x + (size_t)b * 64 * WLEN;
  for (int idx = tid; idx < 8 * 130; idx += 512) {
    int ig = idx / 130;
    int p = idx - ig * 130;
    int w = w_base - 1 + p;
    short8 v = {0, 0, 0, 0, 0, 0, 0, 0};
    if ((unsigned)w < (unsigned)WLEN) {
      const float* src = xb + (size_t)(ig * 8) * WLEN + w;
#pragma unroll
      for (int e = 0; e < 8; ++e) v[e] = f2bf(src[(size_t)e * WLEN]);
    }
    *(short8*)(xs + idx * 8) = v;
  }
  __syncthreads();

  floatx4 acc[4][2];
#pragma unroll
  for (int ms = 0; ms < 4; ++ms)
#pragma unroll
    for (int ns = 0; ns < 2; ++ns) acc[ms][ns] = (floatx4){0.f, 0.f, 0.f, 0.f};

#pragma unroll
  for (int q = 0; q < 2; ++q) {
#pragma unroll
    for (int k = 0; k < 3; ++k) {
      short8 af[4];
      const short* wk =
          wp1 + ((size_t)(k * 8 + q * 4 + kg) * 128 + oh * 64 + ln) * 8;
#pragma unroll
      for (int ms = 0; ms < 4; ++ms)
        af[ms] = *(const short8*)(wk + (size_t)ms * 16 * 8);
#pragma unroll
      for (int ns = 0; ns < 2; ++ns) {
        short8 bf = *(const short8*)(
            xs + ((q * 4 + kg) * 130 + wq * 32 + ns * 16 + ln + k) * 8);
#pragma unroll
        for (int ms = 0; ms < 4; ++ms)
          acc[ms][ns] = __builtin_amdgcn_mfma_f32_16x16x32_bf16(
              af[ms], bf, acc[ms][ns], 0, 0, 0);
      }
    }
  }

  // routing1 scalar
  float zs = 0.f;
#pragma unroll
  for (int qq = 0; qq < 8; ++qq) zs += racc1[b * 8 + qq];
  float z = zs * (1.f / (float)WLEN) + fcb[0];
  float r = 1.f / (1.f + expf(-z));

  float rsum = 0.f;  // routing2 partial: sum y*fcw2[o] over this thread's outputs
#pragma unroll
  for (int ms = 0; ms < 4; ++ms) {
    const int o0 = oh * 64 + ms * 16 + kg * 4;
    float a_[4], c_[4], fw[4];
#pragma unroll
    for (int rr = 0; rr < 4; ++rr) {
      int o = o0 + rr;
      float s = g[o] * rsqrtf(rv[o] + 1e-5f);
      a_[rr] = r * s;
      c_[rr] = (r * bias[o] - rm[o]) * s + be[o];
      fw[rr] = fcw2[o];
    }
#pragma unroll
    for (int ns = 0; ns < 2; ++ns) {
      int w = w_base + wq * 32 + ns * 16 + ln;
      short4v pk;
#pragma unroll
      for (int rr = 0; rr < 4; ++rr) {
        float v = acc[ms][ns][rr] * a_[rr] + c_[rr];
        v = v >= 0.f ? v : 0.1f * v;
        rsum += v * fw[rr];
        pk[rr] = f2bf(v);
      }
      *(short4v*)(y1p + ((size_t)(b * 32 + (o0 >> 2)) * WLEN + w) * 4) = pk;
    }
  }

  red[tid] = rsum;
  __syncthreads();
  for (int s = 256; s > 0; s >>= 1) {
    if (tid < s) red[tid] += red[tid + s];
    __syncthreads();
  }
  if (tid == 0) racc2[b * 16 + blockIdx.x] = red[0];
}

// ---------------------------------------------------------------------------
// conv2: y1p bf16 [b][o/4][w][4] -> out fp32 pooled (B,256,1024).
// block = 512 thr (8 waves), tile 256o x 128w; wave = 64o x 64w (4ms x 4ns).
// grid (16, 32).
// ---------------------------------------------------------------------------
__global__ __launch_bounds__(512) void conv2_mfma(
    const short* __restrict__ y1p, const short* __restrict__ wp2,
    const float* __restrict__ bias, const float* __restrict__ g,
    const float* __restrict__ be, const float* __restrict__ rm,
    const float* __restrict__ rv, const float* __restrict__ racc2,
    const float* __restrict__ fcb, float* __restrict__ out) {
  const int b = blockIdx.y;
  const int w_base = blockIdx.x * 128;
  const int tid = threadIdx.x;
  const int wave = tid >> 6, lane = tid & 63;
  const int ln = lane & 15, kg = lane >> 4;
  const int oq = wave & 3, wh = wave >> 2;

  __shared__ short xs[16 * 130 * 8];  // 33.3 KB

  const short* yb = y1p + (size_t)b * 32 * WLEN * 4;
  for (int idx = tid; idx < 16 * 130; idx += 512) {
    int ig = idx / 130;
    int p = idx - ig * 130;
    int w = w_base - 1 + p;
    short8 v = {0, 0, 0, 0, 0, 0, 0, 0};
    if ((unsigned)w < (unsigned)WLEN) {
      short4v a = *(const short4v*)(yb + ((size_t)(ig * 2) * WLEN + w) * 4);
      short4v c = *(const short4v*)(yb + ((size_t)(ig * 2 + 1) * WLEN + w) * 4);
      v[0] = a[0]; v[1] = a[1]; v[2] = a[2]; v[3] = a[3];
      v[4] = c[0]; v[5] = c[1]; v[6] = c[2]; v[7] = c[3];
    }
    *(short8*)(xs + idx * 8) = v;
  }
  __syncthreads();

  floatx4 acc[4][4];
#pragma unroll
  for (int ms = 0; ms < 4; ++ms)
#pragma unroll
    for (int ns = 0; ns < 4; ++ns) acc[ms][ns] = (floatx4){0.f, 0.f, 0.f, 0.f};

#pragma unroll
  for (int q = 0; q < 4; ++q) {
#pragma unroll
    for (int k = 0; k < 3; ++k) {
      short8 af[4];
      const short* wk =
          wp2 + ((size_t)(k * 16 + q * 4 + kg) * 256 + oq * 64 + ln) * 8;
#pragma unroll
      for (int ms = 0; ms < 4; ++ms)
        af[ms] = *(const short8*)(wk + (size_t)ms * 16 * 8);
#pragma unroll
      for (int ns = 0; ns < 4; ++ns) {
        short8 bf = *(const short8*)(
            xs + ((q * 4 + kg) * 130 + wh * 64 + ns * 16 + ln + k) * 8);
#pragma unroll
        for (int ms = 0; ms < 4; ++ms)
          acc[ms][ns] = __builtin_amdgcn_mfma_f32_16x16x32_bf16(
              af[ms], bf, acc[ms][ns], 0, 0, 0);
      }
    }
  }

  // routing2 scalar
  float zs = 0.f;
#pragma unroll
  for (int t = 0; t < 16; ++t) zs += racc2[b * 16 + t];
  float z = zs * (1.f / (float)WLEN) + fcb[0];
  float r = 1.f / (1.f + expf(-z));

#pragma unroll
  for (int ms = 0; ms < 4; ++ms) {
    const int o0 = oq * 64 + ms * 16 + kg * 4;
    float a_[4], c_[4];
#pragma unroll
    for (int rr = 0; rr < 4; ++rr) {
      int o = o0 + rr;
      float s = g[o] * rsqrtf(rv[o] + 1e-5f);
      a_[rr] = r * s;
      c_[rr] = (r * bias[o] - rm[o]) * s + be[o];
    }
#pragma unroll
    for (int np = 0; np < 2; ++np) {  // ns pairs (0,1) and (2,3)
      float m0[4], m1[4];
#pragma unroll
      for (int half = 0; half < 2; ++half) {
        int ns = np * 2 + half;
#pragma unroll
        for (int rr = 0; rr < 4; ++rr) {
          float v = acc[ms][ns][rr] * a_[rr] + c_[rr];
          v = v >= 0.f ? v : 0.1f * v;
          float m = fmaxf(v, __shfl_xor(v, 1));
          if (half == 0) m0[rr] = m; else m1[rr] = m;
        }
      }
      const int pc = (w_base >> 1) + wh * 32 + np * 16 + ln;
#pragma unroll
      for (int rr = 0; rr < 4; ++rr) {
        int src = kg * 16 + ((ln & 7) << 1);
        float aa = __shfl(m0[rr], src);
        float bb = __shfl(m1[rr], src);
        float val = (ln < 8) ? aa : bb;
        out[((size_t)(b * 256 + o0 + rr)) * (WLEN / 2) + pc] = val;
      }
    }
  }
}

// ---------------------------------------------------------------------------
extern "C" void kernel_launch(void* const* d_in, const int* in_sizes, int n_in,
                              void* d_out, int out_size, void* d_ws, size_t ws_size,
                              hipStream_t stream) {
  const float* x    = (const float*)d_in[0];
  const float* w1   = (const float*)d_in[1];
  const float* b1   = (const float*)d_in[2];
  const float* fcw1 = (const float*)d_in[3];
  const float* fcb1 = (const float*)d_in[4];
  const float* g1   = (const float*)d_in[5];
  const float* be1  = (const float*)d_in[6];
  const float* rm1  = (const float*)d_in[7];
  const float* rv1  = (const float*)d_in[8];
  const float* w2   = (const float*)d_in[9];
  const float* b2   = (const float*)d_in[10];
  const float* fcw2 = (const float*)d_in[11];
  const float* fcb2 = (const float*)d_in[12];
  const float* g2   = (const float*)d_in[13];
  const float* be2  = (const float*)d_in[14];
  const float* rm2  = (const float*)d_in[15];
  const float* rv2  = (const float*)d_in[16];

  float* out = (float*)d_out;

  // workspace layout
  char* ws = (char*)d_ws;
  short* y1p = (short*)ws;                                   // 32*32*2048*4*2 = 16 MiB
  short* wp1 = (short*)(ws + (size_t)16 * 1024 * 1024);      // 48 KiB
  short* wp2 = (short*)(ws + (size_t)16 * 1024 * 1024 + 64 * 1024);  // 192 KiB
  float* racc1 = (float*)(ws + (size_t)16 * 1024 * 1024 + 512 * 1024);  // 256 f
  float* racc2 = racc1 + 256;                                // 512 f

  fused_prep<<<316, 256, 0, stream>>>(w1, w2, x, fcw1, wp1, wp2, racc1);
  conv1_mfma<<<dim3(16, 32), 512, 0, stream>>>(
      x, wp1, b1, g1, be1, rm1, rv1, racc1, fcb1, fcw2, y1p, racc2);
  conv2_mfma<<<dim3(16, 32), 512, 0, stream>>>(
      y1p, wp2, b2, g2, be2, rm2, rv2, racc2, fcb2, out);
}